// Round 10
// baseline (419.625 us; speedup 1.0000x reference)
//
#include <hip/hip_runtime.h>

#define D 256

typedef float f32x4 __attribute__((ext_vector_type(4)));
typedef _Float16 f16x8 __attribute__((ext_vector_type(8)));

// ---------------------------------------------------------------- k_edges
__global__ void k_edges(const int* __restrict__ ei, const int* __restrict__ cl,
                        float* __restrict__ degx, int E) {
    int e = blockIdx.x * blockDim.x + threadIdx.x;
    if (e >= E) return;
    int s = ei[e];
    int d = ei[E + e];
    if (cl[s] == cl[d])
        unsafeAtomicAdd(&degx[d], 1.0f);   // HW global_atomic_add_f32, exact ints
}

// ---------------------------------------------------------------- k_init
// rows with degx>0: out_row = X_row / (degx+1), and mark cluster active
// (degx[n]>0 implies cluster cl[n] has an intra edge; idempotent store).
__global__ void k_init(const float* __restrict__ X, const float* __restrict__ degx,
                       const int* __restrict__ cl, int* __restrict__ activeC,
                       float* __restrict__ out, int N) {
    int i = blockIdx.x * blockDim.x + threadIdx.x;
    int lane = threadIdx.x & 63;
    float dx = 0.0f;
    bool hit = false;
    if (i < N) {
        dx = degx[i];
        hit = dx > 0.0f;
        if (hit) activeC[cl[i]] = 1;
    }
    unsigned long long m = __ballot(hit);
    int base = i - lane;
    while (m) {
        int b = __ffsll((long long)m) - 1;
        m &= m - 1;
        int r = base + b;
        float inv = 1.0f / (__shfl(dx, b) + 1.0f);
        float4 x = *(const float4*)(X + (size_t)r * D + lane * 4);
        x.x *= inv; x.y *= inv; x.z *= inv; x.w *= inv;
        *(float4*)(out + (size_t)r * D + lane * 4) = x;
    }
}

// ---------------------------------------------------------------- k_scatter
__global__ void k_scatter(const int* __restrict__ ei, const int* __restrict__ cl,
                          const float* __restrict__ degx, const float* __restrict__ X,
                          float* __restrict__ out, int E) {
    int e = blockIdx.x * blockDim.x + threadIdx.x;
    int lane = threadIdx.x & 63;
    int s = 0, d = 0;
    bool intra = false;
    if (e < E) {
        s = ei[e];
        d = ei[E + e];
        intra = (cl[s] == cl[d]);
    }
    unsigned long long mask = __ballot(intra);
    while (mask) {
        int b = __ffsll((long long)mask) - 1;
        mask &= mask - 1;
        int ss = __shfl(s, b);
        int dd = __shfl(d, b);
        float norm = rsqrtf((degx[ss] + 1.0f) * (degx[dd] + 1.0f));
        float4 xv = *(const float4*)(X + (size_t)ss * D + lane * 4);
        float* op = out + (size_t)dd * D + lane * 4;
        unsafeAtomicAdd(op + 0, norm * xv.x);
        unsafeAtomicAdd(op + 1, norm * xv.y);
        unsafeAtomicAdd(op + 2, norm * xv.z);
        unsafeAtomicAdd(op + 3, norm * xv.w);
    }
}

// ---------------------------------------------------------------- k_prepw
// Pack W (f32 [k][n]) into f16 fragment layout (unchanged; operand-role
// symmetric):  Wp[((ks*16+ct)*64 + lane)*8 + i] = W[ks*32 + h*8 + i][ct*16+cn],
// lane = h*16 + cn.
__global__ void k_prepw(const float* __restrict__ W, _Float16* __restrict__ Wp) {
    int idx = blockIdx.x * blockDim.x + threadIdx.x;
    if (idx >= D * D) return;
    int k = idx >> 8, n = idx & 255;
    int ks = k >> 5, kk = k & 31;
    int h = kk >> 3, i = kk & 7;
    int ct = n >> 4, cn = n & 15;
    int lane = h * 16 + cn;
    Wp[(((ks * 16 + ct) * 64 + lane) << 3) + i] = (_Float16)W[idx];
}

// ---------------------------------------------------------------- k_gemm
// 256 blocks x 1024 thr. Full W (128 KB) + bias (1 KB) in LDS, staged once.
// Task = (16-row tile, col-half). Wave owns 16 rows x 128 cols (acc 8xf32x4).
// SWAPPED mfma(wf, af): lane holds C[row = t*16+(lane&15)][4 consecutive cols]
// -> float4 stores. A software-pipelined across tasks: 4-slot f32 window,
// cvt lands in-place into curA; every wave keeps loads in flight during MFMA.
// Global sweep order: task = blk*16 + wid + r*4096 (dense band, L2-friendly).
__global__ __launch_bounds__(1024, 4) void k_gemm(
        const _Float16* __restrict__ Wp, const float* __restrict__ bias,
        const float* __restrict__ X, const float* __restrict__ degx,
        const int* __restrict__ cl, const int* __restrict__ activeC,
        float* __restrict__ out, int N) {
    extern __shared__ char smem[];
    _Float16* Wl = (_Float16*)smem;          // 128 KB packed W
    float* Bl = (float*)(smem + 131072);     // 1 KB bias

    int tid = threadIdx.x;
    int lane = tid & 63;
    int wid  = tid >> 6;
    int rA = lane & 15;   // node row within tile (B-operand col after swap)
    int h  = lane >> 4;   // k-subgroup / output col subgroup

    if (tid < 256) Bl[tid] = bias[tid];
    {
        const char* src = (const char*)Wp + tid * 16;
        #pragma unroll
        for (int it = 0; it < 8; ++it) {
            __builtin_amdgcn_global_load_lds(
                (const __attribute__((address_space(1))) void*)(src + it * 16384),
                (__attribute__((address_space(3))) void*)(smem + tid * 16 + it * 16384),
                16, 0, 0);
        }
    }
    __syncthreads();

    const int T2 = ((N + 15) >> 4) << 1;      // tasks = tiles * 2 col-halves
    const int STRIDE = 4096;                  // 256 blocks * 16 waves

    int t = (int)blockIdx.x * 16 + wid;
    if (t >= T2) return;
    const int half = t & 1;                   // loop-invariant (STRIDE even)
    const int colbase = half * 128 + h * 4;   // this lane's first output col

    // ---- prologue: load task t's first half directly, issue second half ----
    {
        long r0 = (long)(t >> 1) * 16 + rA;
        if (r0 > (long)N - 1) r0 = (long)N - 1;
        const float* arow0 = ((degx[r0] > 0.0f) ? out : X) + r0 * D;
        // curA[0..3] direct
        // (declared below; fill via the same pattern)
        // second half pairs go into the rolling window
        // -- code continues below with declarations --
        // placeholder comment; actual code follows
        (void)arow0;
    }

    f16x8 curA[8];
    float4 Pa[4], Pb[4];
    {
        long r0 = (long)(t >> 1) * 16 + rA;
        if (r0 > (long)N - 1) r0 = (long)N - 1;
        const float* arow0 = ((degx[r0] > 0.0f) ? out : X) + r0 * D;
        #pragma unroll
        for (int ks = 0; ks < 4; ++ks) {
            float4 a0 = *(const float4*)(arow0 + ks * 32 + h * 8);
            float4 a1 = *(const float4*)(arow0 + ks * 32 + h * 8 + 4);
            f16x8 af;
            af[0]=(_Float16)a0.x; af[1]=(_Float16)a0.y; af[2]=(_Float16)a0.z; af[3]=(_Float16)a0.w;
            af[4]=(_Float16)a1.x; af[5]=(_Float16)a1.y; af[6]=(_Float16)a1.z; af[7]=(_Float16)a1.w;
            curA[ks] = af;
        }
        #pragma unroll
        for (int s = 0; s < 4; ++s) {
            Pa[s] = *(const float4*)(arow0 + (4 + s) * 32 + h * 8);
            Pb[s] = *(const float4*)(arow0 + (4 + s) * 32 + h * 8 + 4);
        }
    }

    // degx prefetch for next task (clamped to task 0 when out of range so the
    // (dgx, row) pair stays consistent; the resulting loads are unused).
    int tn = t + STRIDE;
    int tnc = (tn < T2) ? tn : 0;
    long rn = (long)(tnc >> 1) * 16 + rA;
    float dgxN = degx[rn];

    const char* WlB = (const char*)Wl + lane * 16;

    for (;;) {
        const int tile = t >> 1;
        const float* arowN = ((dgxN > 0.0f) ? out : X) + rn * D;

        // prefetch degx for task after next
        int t2 = t + 2 * STRIDE;
        int t2c = (t2 < T2) ? t2 : 0;
        long r2 = (long)(t2c >> 1) * 16 + rA;
        float dgx2 = degx[r2];

        // activity per lane's row
        long rr = (long)tile * 16 + rA;
        long rc = (rr < (long)N) ? rr : (long)N - 1;
        int act = activeC[cl[rc]];
        unsigned long long bad = __ballot(act == 0 || rr >= (long)N);

        // acc = bias (LDS broadcast)
        f32x4 acc[8];
        #pragma unroll
        for (int c = 0; c < 8; ++c)
            acc[c] = *(const f32x4*)(Bl + colbase + c * 16);

        // ---- pipelined ks loop ----
        #pragma unroll
        for (int ks = 0; ks < 8; ++ks) {
            const int s = ks & 3;
            // cvt window slot -> curA (in place; slot data is:
            //   ks<4: current task's ks+4 fragment; ks>=4: next task's ks-4)
            {
                float4 a0 = Pa[s], a1 = Pb[s];
                f16x8 af;
                af[0]=(_Float16)a0.x; af[1]=(_Float16)a0.y; af[2]=(_Float16)a0.z; af[3]=(_Float16)a0.w;
                af[4]=(_Float16)a1.x; af[5]=(_Float16)a1.y; af[6]=(_Float16)a1.z; af[7]=(_Float16)a1.w;
                curA[(ks >= 4) ? (ks - 4) : (ks + 4)] = af;
            }
            // issue next task's pair(ks) into the freed slot
            Pa[s] = *(const float4*)(arowN + ks * 32 + h * 8);
            Pb[s] = *(const float4*)(arowN + ks * 32 + h * 8 + 4);
            // 8 MFMAs for this ks (swapped operands)
            f16x8 af = curA[ks];
            #pragma unroll
            for (int c = 0; c < 8; ++c) {
                f16x8 wf = *(const f16x8*)(WlB + (size_t)(ks * 16 + half * 8 + c) * 1024);
                acc[c] = __builtin_amdgcn_mfma_f32_16x16x32_f16(wf, af, acc[c], 0, 0, 0);
            }
        }

        // ---- epilogue: float4 per ct, lane row = rr, cols colbase + c*16 ----
        float* orow = out + rc * D + colbase;
        if (bad == 0ULL) {
            #pragma unroll
            for (int c = 0; c < 8; ++c)
                *(float4*)(orow + c * 16) =
                    (float4){acc[c][0], acc[c][1], acc[c][2], acc[c][3]};
        } else if (rr < (long)N) {
            const float* xrow = X + rc * D + colbase;
            #pragma unroll
            for (int c = 0; c < 8; ++c) {
                float4 v;
                if (act) v = (float4){acc[c][0], acc[c][1], acc[c][2], acc[c][3]};
                else     v = *(const float4*)(xrow + c * 16);
                *(float4*)(orow + c * 16) = v;
            }
        }

        t = tn;
        if (t >= T2) break;
        tn = t + STRIDE;
        tnc = (tn < T2) ? tn : 0;
        rn = (long)(tnc >> 1) * 16 + rA;
        dgxN = dgx2;
    }
}

// ---------------------------------------------------------------- launch
extern "C" void kernel_launch(void* const* d_in, const int* in_sizes, int n_in,
                              void* d_out, int out_size, void* d_ws, size_t ws_size,
                              hipStream_t stream) {
    const float* X    = (const float*)d_in[0];
    const float* W    = (const float*)d_in[1];
    const float* bias = (const float*)d_in[2];
    const int*   cl   = (const int*)d_in[3];
    const int*   ei   = (const int*)d_in[4];
    int N = in_sizes[3];
    int E = in_sizes[4] / 2;
    float* out = (float*)d_out;

    char* ws = (char*)d_ws;
    float* degx = (float*)ws;                                  // N floats, zeroed
    size_t off = ((size_t)N * sizeof(float) + 255) & ~(size_t)255;
    int* activeC = (int*)(ws + off);                           // 64 ints, zeroed
    size_t zbytes = off + 256;
    _Float16* Wp = (_Float16*)(ws + ((zbytes + 255) & ~(size_t)255));  // 128 KB

    hipFuncSetAttribute((const void*)k_gemm,
                        hipFuncAttributeMaxDynamicSharedMemorySize, 135168);

    hipMemsetAsync(ws, 0, zbytes, stream);
    k_prepw<<<(D * D + 255) / 256, 256, 0, stream>>>(W, Wp);
    k_edges<<<(E + 255) / 256, 256, 0, stream>>>(ei, cl, degx, E);
    k_init<<<(N + 255) / 256, 256, 0, stream>>>(X, degx, cl, activeC, out, N);
    k_scatter<<<(E + 255) / 256, 256, 0, stream>>>(ei, cl, degx, X, out, E);
    k_gemm<<<256, 1024, 132096, stream>>>(Wp, bias, X, degx, cl, activeC, out, N);
}

// Round 11
// 416.037 us; speedup vs baseline: 1.0086x; 1.0086x over previous
//
#include <hip/hip_runtime.h>

#define D 256

typedef float f32x4 __attribute__((ext_vector_type(4)));
typedef _Float16 f16x8 __attribute__((ext_vector_type(8)));

// ---------------------------------------------------------------- k_edges
__global__ void k_edges(const int* __restrict__ ei, const int* __restrict__ cl,
                        float* __restrict__ degx, int E) {
    int e = blockIdx.x * blockDim.x + threadIdx.x;
    if (e >= E) return;
    int s = ei[e];
    int d = ei[E + e];
    if (cl[s] == cl[d])
        unsafeAtomicAdd(&degx[d], 1.0f);   // HW global_atomic_add_f32, exact ints
}

// ---------------------------------------------------------------- k_init
// rows with degx>0: out_row = X_row / (degx+1), and mark cluster active
// (degx[n]>0 implies cluster cl[n] has an intra edge; idempotent store).
__global__ void k_init(const float* __restrict__ X, const float* __restrict__ degx,
                       const int* __restrict__ cl, int* __restrict__ activeC,
                       float* __restrict__ out, int N) {
    int i = blockIdx.x * blockDim.x + threadIdx.x;
    int lane = threadIdx.x & 63;
    float dx = 0.0f;
    bool hit = false;
    if (i < N) {
        dx = degx[i];
        hit = dx > 0.0f;
        if (hit) activeC[cl[i]] = 1;
    }
    unsigned long long m = __ballot(hit);
    int base = i - lane;
    while (m) {
        int b = __ffsll((long long)m) - 1;
        m &= m - 1;
        int r = base + b;
        float inv = 1.0f / (__shfl(dx, b) + 1.0f);
        float4 x = *(const float4*)(X + (size_t)r * D + lane * 4);
        x.x *= inv; x.y *= inv; x.z *= inv; x.w *= inv;
        *(float4*)(out + (size_t)r * D + lane * 4) = x;
    }
}

// ---------------------------------------------------------------- k_scatter
__global__ void k_scatter(const int* __restrict__ ei, const int* __restrict__ cl,
                          const float* __restrict__ degx, const float* __restrict__ X,
                          float* __restrict__ out, int E) {
    int e = blockIdx.x * blockDim.x + threadIdx.x;
    int lane = threadIdx.x & 63;
    int s = 0, d = 0;
    bool intra = false;
    if (e < E) {
        s = ei[e];
        d = ei[E + e];
        intra = (cl[s] == cl[d]);
    }
    unsigned long long mask = __ballot(intra);
    while (mask) {
        int b = __ffsll((long long)mask) - 1;
        mask &= mask - 1;
        int ss = __shfl(s, b);
        int dd = __shfl(d, b);
        float norm = rsqrtf((degx[ss] + 1.0f) * (degx[dd] + 1.0f));
        float4 xv = *(const float4*)(X + (size_t)ss * D + lane * 4);
        float* op = out + (size_t)dd * D + lane * 4;
        unsafeAtomicAdd(op + 0, norm * xv.x);
        unsafeAtomicAdd(op + 1, norm * xv.y);
        unsafeAtomicAdd(op + 2, norm * xv.z);
        unsafeAtomicAdd(op + 3, norm * xv.w);
    }
}

// ---------------------------------------------------------------- k_prepw
// Pack W (f32 [k][n]) into f16 fragment layout (unchanged; operand-role
// symmetric):  Wp[((ks*16+ct)*64 + lane)*8 + i] = W[ks*32 + h*8 + i][ct*16+cn],
// lane = h*16 + cn.
__global__ void k_prepw(const float* __restrict__ W, _Float16* __restrict__ Wp) {
    int idx = blockIdx.x * blockDim.x + threadIdx.x;
    if (idx >= D * D) return;
    int k = idx >> 8, n = idx & 255;
    int ks = k >> 5, kk = k & 31;
    int h = kk >> 3, i = kk & 7;
    int ct = n >> 4, cn = n & 15;
    int lane = h * 16 + cn;
    Wp[(((ks * 16 + ct) * 64 + lane) << 3) + i] = (_Float16)W[idx];
}

// ---------------------------------------------------------------- k_gemm
// 256 blocks x 1024 thr. Full W (128 KB) + bias (1 KB) in LDS, staged once.
// Task = (16-row tile, col-half). Wave owns 16 rows x 128 cols (acc 8xf32x4).
// SWAPPED mfma(wf, af): lane holds C[row = t*16+(lane&15)][4 consecutive cols]
// -> float4 stores. A software-pipelined across tasks: 4-slot f32 window,
// cvt lands in-place into curA; every wave keeps loads in flight during MFMA.
// Global sweep order: task = blk*16 + wid + r*4096 (dense band, L2-friendly).
__global__ __launch_bounds__(1024, 4) void k_gemm(
        const _Float16* __restrict__ Wp, const float* __restrict__ bias,
        const float* __restrict__ X, const float* __restrict__ degx,
        const int* __restrict__ cl, const int* __restrict__ activeC,
        float* __restrict__ out, int N) {
    extern __shared__ char smem[];
    _Float16* Wl = (_Float16*)smem;          // 128 KB packed W
    float* Bl = (float*)(smem + 131072);     // 1 KB bias

    int tid = threadIdx.x;
    int lane = tid & 63;
    int wid  = tid >> 6;
    int rA = lane & 15;   // node row within tile (B-operand col after swap)
    int h  = lane >> 4;   // k-subgroup / output col subgroup

    if (tid < 256) Bl[tid] = bias[tid];
    {
        const char* src = (const char*)Wp + tid * 16;
        #pragma unroll
        for (int it = 0; it < 8; ++it) {
            __builtin_amdgcn_global_load_lds(
                (const __attribute__((address_space(1))) void*)(src + it * 16384),
                (__attribute__((address_space(3))) void*)(smem + tid * 16 + it * 16384),
                16, 0, 0);
        }
    }
    __syncthreads();

    const int T2 = ((N + 15) >> 4) << 1;      // tasks = tiles * 2 col-halves
    const int STRIDE = 4096;                  // 256 blocks * 16 waves

    int t = (int)blockIdx.x * 16 + wid;
    if (t >= T2) return;
    const int half = t & 1;                   // loop-invariant (STRIDE even)
    const int colbase = half * 128 + h * 4;   // this lane's first output col

    // ---- prologue: load task t's first half directly, issue second half ----
    {
        long r0 = (long)(t >> 1) * 16 + rA;
        if (r0 > (long)N - 1) r0 = (long)N - 1;
        const float* arow0 = ((degx[r0] > 0.0f) ? out : X) + r0 * D;
        // curA[0..3] direct
        // (declared below; fill via the same pattern)
        // second half pairs go into the rolling window
        // -- code continues below with declarations --
        // placeholder comment; actual code follows
        (void)arow0;
    }

    f16x8 curA[8];
    float4 Pa[4], Pb[4];
    {
        long r0 = (long)(t >> 1) * 16 + rA;
        if (r0 > (long)N - 1) r0 = (long)N - 1;
        const float* arow0 = ((degx[r0] > 0.0f) ? out : X) + r0 * D;
        #pragma unroll
        for (int ks = 0; ks < 4; ++ks) {
            float4 a0 = *(const float4*)(arow0 + ks * 32 + h * 8);
            float4 a1 = *(const float4*)(arow0 + ks * 32 + h * 8 + 4);
            f16x8 af;
            af[0]=(_Float16)a0.x; af[1]=(_Float16)a0.y; af[2]=(_Float16)a0.z; af[3]=(_Float16)a0.w;
            af[4]=(_Float16)a1.x; af[5]=(_Float16)a1.y; af[6]=(_Float16)a1.z; af[7]=(_Float16)a1.w;
            curA[ks] = af;
        }
        #pragma unroll
        for (int s = 0; s < 4; ++s) {
            Pa[s] = *(const float4*)(arow0 + (4 + s) * 32 + h * 8);
            Pb[s] = *(const float4*)(arow0 + (4 + s) * 32 + h * 8 + 4);
        }
    }

    // degx prefetch for next task (clamped to task 0 when out of range so the
    // (dgx, row) pair stays consistent; the resulting loads are unused).
    int tn = t + STRIDE;
    int tnc = (tn < T2) ? tn : 0;
    long rn = (long)(tnc >> 1) * 16 + rA;
    float dgxN = degx[rn];

    const char* WlB = (const char*)Wl + lane * 16;

    for (;;) {
        const int tile = t >> 1;
        const float* arowN = ((dgxN > 0.0f) ? out : X) + rn * D;

        // prefetch degx for task after next
        int t2 = t + 2 * STRIDE;
        int t2c = (t2 < T2) ? t2 : 0;
        long r2 = (long)(t2c >> 1) * 16 + rA;
        float dgx2 = degx[r2];

        // activity per lane's row
        long rr = (long)tile * 16 + rA;
        long rc = (rr < (long)N) ? rr : (long)N - 1;
        int act = activeC[cl[rc]];
        unsigned long long bad = __ballot(act == 0 || rr >= (long)N);

        // acc = bias (LDS broadcast)
        f32x4 acc[8];
        #pragma unroll
        for (int c = 0; c < 8; ++c)
            acc[c] = *(const f32x4*)(Bl + colbase + c * 16);

        // ---- pipelined ks loop ----
        #pragma unroll
        for (int ks = 0; ks < 8; ++ks) {
            const int s = ks & 3;
            // cvt window slot -> curA (in place; slot data is:
            //   ks<4: current task's ks+4 fragment; ks>=4: next task's ks-4)
            {
                float4 a0 = Pa[s], a1 = Pb[s];
                f16x8 af;
                af[0]=(_Float16)a0.x; af[1]=(_Float16)a0.y; af[2]=(_Float16)a0.z; af[3]=(_Float16)a0.w;
                af[4]=(_Float16)a1.x; af[5]=(_Float16)a1.y; af[6]=(_Float16)a1.z; af[7]=(_Float16)a1.w;
                curA[(ks >= 4) ? (ks - 4) : (ks + 4)] = af;
            }
            // issue next task's pair(ks) into the freed slot
            Pa[s] = *(const float4*)(arowN + ks * 32 + h * 8);
            Pb[s] = *(const float4*)(arowN + ks * 32 + h * 8 + 4);
            // 8 MFMAs for this ks (swapped operands)
            f16x8 af = curA[ks];
            #pragma unroll
            for (int c = 0; c < 8; ++c) {
                f16x8 wf = *(const f16x8*)(WlB + (size_t)(ks * 16 + half * 8 + c) * 1024);
                acc[c] = __builtin_amdgcn_mfma_f32_16x16x32_f16(wf, af, acc[c], 0, 0, 0);
            }
        }

        // ---- epilogue: float4 per ct, lane row = rr, cols colbase + c*16 ----
        float* orow = out + rc * D + colbase;
        if (bad == 0ULL) {
            #pragma unroll
            for (int c = 0; c < 8; ++c)
                *(float4*)(orow + c * 16) =
                    (float4){acc[c][0], acc[c][1], acc[c][2], acc[c][3]};
        } else if (rr < (long)N) {
            const float* xrow = X + rc * D + colbase;
            #pragma unroll
            for (int c = 0; c < 8; ++c) {
                float4 v;
                if (act) v = (float4){acc[c][0], acc[c][1], acc[c][2], acc[c][3]};
                else     v = *(const float4*)(xrow + c * 16);
                *(float4*)(orow + c * 16) = v;
            }
        }

        t = tn;
        if (t >= T2) break;
        tn = t + STRIDE;
        tnc = (tn < T2) ? tn : 0;
        rn = (long)(tnc >> 1) * 16 + rA;
        dgxN = dgx2;
    }
}

// ---------------------------------------------------------------- launch
extern "C" void kernel_launch(void* const* d_in, const int* in_sizes, int n_in,
                              void* d_out, int out_size, void* d_ws, size_t ws_size,
                              hipStream_t stream) {
    const float* X    = (const float*)d_in[0];
    const float* W    = (const float*)d_in[1];
    const float* bias = (const float*)d_in[2];
    const int*   cl   = (const int*)d_in[3];
    const int*   ei   = (const int*)d_in[4];
    int N = in_sizes[3];
    int E = in_sizes[4] / 2;
    float* out = (float*)d_out;

    char* ws = (char*)d_ws;
    float* degx = (float*)ws;                                  // N floats, zeroed
    size_t off = ((size_t)N * sizeof(float) + 255) & ~(size_t)255;
    int* activeC = (int*)(ws + off);                           // 64 ints, zeroed
    size_t zbytes = off + 256;
    _Float16* Wp = (_Float16*)(ws + ((zbytes + 255) & ~(size_t)255));  // 128 KB

    hipFuncSetAttribute((const void*)k_gemm,
                        hipFuncAttributeMaxDynamicSharedMemorySize, 135168);

    hipMemsetAsync(ws, 0, zbytes, stream);
    k_prepw<<<(D * D + 255) / 256, 256, 0, stream>>>(W, Wp);
    k_edges<<<(E + 255) / 256, 256, 0, stream>>>(ei, cl, degx, E);
    k_init<<<(N + 255) / 256, 256, 0, stream>>>(X, degx, cl, activeC, out, N);
    k_scatter<<<(E + 255) / 256, 256, 0, stream>>>(ei, cl, degx, X, out, E);
    k_gemm<<<256, 1024, 132096, stream>>>(Wp, bias, X, degx, cl, activeC, out, N);
}